// Round 5
// baseline (200.707 us; speedup 1.0000x reference)
//
#include <hip/hip_runtime.h>
#include <hip/hip_bf16.h>

// Problem constants (from reference)
#define BATCH   64
#define NMEL    80
#define TFRAME  1000
#define NDEC    1000
#define TENC    200
#define NSPK    100
#define NAUG    10

// Element counts
#define N_MEL   (BATCH * NMEL * TFRAME)     // 5,120,000
#define N_GATE  (BATCH * TFRAME)            // 64,000
#define N_ALIGN (BATCH * NDEC * TENC)       // 12,800,000

// 4-element (16 B fp32) vector units
#define U_MEL   (N_MEL / 4)                 // 1,280,000
#define U_GATE  (N_GATE / 4)                // 16,000
#define U_ALIGN (N_ALIGN / 4)               // 3,200,000

#define BLOCK 256

// Exact-fit straight-line sections (R5): branch-free per block, all loads
// issued before any waitcnt -> max bytes in flight (R4 was latency-starved:
// VALUBusy 9%, HBM 10%, one latency exposure per branchy loop iteration).
#define MEL_NB   2500                        // 512 units/block  (2 float4/lane x 3 streams)
#define ALIGN_NB 3125                        // 1024 units/block (4 float4/lane)
#define GATE_NB  16                          // 1024 units/block, bounds-checked
#define MEL_B0   0
#define ALIGN_B0 (MEL_B0 + MEL_NB)           // 2500
#define GATE_B0  (ALIGN_B0 + ALIGN_NB)       // 5625
#define CE_B     (GATE_B0 + GATE_NB)         // 5641
#define GRID     (CE_B + 1)                  // 5642

// ws layout (floats), 64 B spacing per atomic target:
#define WS_MEL   0
#define WS_GATE  16
#define WS_ALIGN 32
#define WS_SPK   48
#define WS_AUG   64

__device__ __forceinline__ float waveReduceSum(float v) {
#pragma unroll
    for (int o = 32; o > 0; o >>= 1) v += __shfl_down(v, o, 64);
    return v;
}

// Native fp32 atomic add (global_atomic_add_f32); cross-XCD correct (R3/R4,
// absmax 0.0). Fire-and-forget: no return value -> no wait in the hot path.
__device__ __forceinline__ void fatomic_add(float* p, float v) {
    unsafeAtomicAdd(p, v);
}

__device__ __forceinline__ void blockReduceAtomic(float v, float* target) {
    __shared__ float smem[4];
    const int lane = threadIdx.x & 63;
    const int wid = threadIdx.x >> 6;
    v = waveReduceSum(v);
    if (lane == 0) smem[wid] = v;
    __syncthreads();
    if (threadIdx.x == 0) {
        fatomic_add(target, smem[0] + smem[1] + smem[2] + smem[3]);
    }
}

__global__ __launch_bounds__(BLOCK) void tacotron2_loss_reduce(
    const float* __restrict__ mel_out,
    const float* __restrict__ mel_post,
    const float* __restrict__ gate_out,
    const float* __restrict__ align,
    const float* __restrict__ spk_out,
    const float* __restrict__ aug_out,
    const float* __restrict__ mel_tgt,
    const float* __restrict__ gate_tgt,
    const float* __restrict__ spk_tgt,
    const float* __restrict__ aug_tgt,
    float* __restrict__ ws)
{
    const int bid = blockIdx.x;
    const int t = threadIdx.x;

    if (bid < ALIGN_B0) {
        // ---- MEL section: straight-line, 6 float4 loads issued up front ----
        const int base = bid * 512 + t;              // float4-unit index
        const float4* ao = (const float4*)mel_out;
        const float4* po = (const float4*)mel_post;
        const float4* to = (const float4*)mel_tgt;
        float4 a0 = ao[base], a1 = ao[base + 256];
        float4 p0 = po[base], p1 = po[base + 256];
        float4 t0 = to[base], t1 = to[base + 256];
        float s = 0.f, d;
        d = a0.x - t0.x; s = fmaf(d, d, s);
        d = a0.y - t0.y; s = fmaf(d, d, s);
        d = a0.z - t0.z; s = fmaf(d, d, s);
        d = a0.w - t0.w; s = fmaf(d, d, s);
        d = p0.x - t0.x; s = fmaf(d, d, s);
        d = p0.y - t0.y; s = fmaf(d, d, s);
        d = p0.z - t0.z; s = fmaf(d, d, s);
        d = p0.w - t0.w; s = fmaf(d, d, s);
        d = a1.x - t1.x; s = fmaf(d, d, s);
        d = a1.y - t1.y; s = fmaf(d, d, s);
        d = a1.z - t1.z; s = fmaf(d, d, s);
        d = a1.w - t1.w; s = fmaf(d, d, s);
        d = p1.x - t1.x; s = fmaf(d, d, s);
        d = p1.y - t1.y; s = fmaf(d, d, s);
        d = p1.z - t1.z; s = fmaf(d, d, s);
        d = p1.w - t1.w; s = fmaf(d, d, s);
        blockReduceAtomic(s, &ws[WS_MEL]);
    } else if (bid < GATE_B0) {
        // ---- ALIGN section: 4 float4 loads up front ----
        const int b = bid - ALIGN_B0;
        const int base = b * 1024 + t;               // float4-unit index
        const float4* av = (const float4*)align;
        float4 A0 = av[base];
        float4 A1 = av[base + 256];
        float4 A2 = av[base + 512];
        float4 A3 = av[base + 768];
        float s = 0.f;
        float4 regs[4] = {A0, A1, A2, A3};
#pragma unroll
        for (int k = 0; k < 4; k++) {
            const int u = base + 256 * k;            // unit; element e = 4u
            const int q = u / 50;                    // e / 200
            const int r = u - q * 50;                // (e % 200) / 4
            const float nf = (float)(q % NDEC) * (1.0f / (float)NDEC);
            const float tb = (float)(4 * r) * (1.0f / (float)TENC);
            const float fa[4] = {regs[k].x, regs[k].y, regs[k].z, regs[k].w};
#pragma unroll
            for (int j = 0; j < 4; j++) {
                float tf_ = tb + (float)j * (1.0f / (float)TENC);
                float d = nf - tf_;
                float g = 1.0f - __expf(d * d * -2.5f);   // 1/K_ALIGN = 2.5
                s = fmaf(fa[j], g, s);
            }
        }
        blockReduceAtomic(s, &ws[WS_ALIGN]);
    } else if (bid < CE_B) {
        // ---- GATE section: 4 predicated float4 loads ----
        const int b = bid - GATE_B0;
        const int base = b * 1024 + t;
        const float4* xo = (const float4*)gate_out;
        const float4* yo = (const float4*)gate_tgt;
        float s = 0.f;
#pragma unroll
        for (int k = 0; k < 4; k++) {
            const int u = base + 256 * k;
            if (u < U_GATE) {
                float4 x = xo[u];
                float4 y = yo[u];
                float fx[4] = {x.x, x.y, x.z, x.w};
                float fy[4] = {y.x, y.y, y.z, y.w};
#pragma unroll
                for (int j = 0; j < 4; j++) {
                    float xx = fx[j];
                    // softplus(x) = max(x,0) + log1p(exp(-|x|))
                    float sp = fmaxf(xx, 0.f) + log1pf(__expf(-fabsf(xx)));
                    s += sp - xx * fy[j];
                }
            }
        }
        blockReduceAtomic(s, &ws[WS_GATE]);
    } else {
        // ---- CE block: wave 0 -> speaker rows, wave 1 -> augment rows ----
        if (t < 64) {
            const int r = t;
            const float* row = spk_out + r * NSPK;
            float mx = -1e30f;
            for (int c = 0; c < NSPK; c++) mx = fmaxf(mx, row[c]);
            float se = 0.f;
            for (int c = 0; c < NSPK; c++) se += __expf(row[c] - mx);
            const float* trow = spk_tgt + r * NSPK;
            float tm = -1e30f; int lab = 0;
            for (int c = 0; c < NSPK; c++) {
                float v = trow[c];
                if (v > tm) { tm = v; lab = c; }
            }
            float loss = -(row[lab] - mx - __logf(se));
            loss = waveReduceSum(loss);
            if (t == 0) fatomic_add(&ws[WS_SPK], loss);
        } else if (t < 128) {
            const int r = t - 64;
            const float* row = aug_out + r * NAUG;
            float mx = -1e30f;
            for (int c = 0; c < NAUG; c++) mx = fmaxf(mx, row[c]);
            float se = 0.f;
            for (int c = 0; c < NAUG; c++) se += __expf(row[c] - mx);
            const float* trow = aug_tgt + r * NAUG;
            float tm = -1e30f; int lab = 0;
            for (int c = 0; c < NAUG; c++) {
                float v = trow[c];
                if (v > tm) { tm = v; lab = c; }
            }
            float loss = -(row[lab] - mx - __logf(se));
            loss = waveReduceSum(loss);
            if (t == 64) fatomic_add(&ws[WS_AUG], loss);
        }
    }
}

// Kernel 2: finalize. One block; kernel boundary = release/acquire. Agent-scope
// atomic loads bypass (possibly stale) per-CU L1.
__global__ __launch_bounds__(64) void tacotron2_loss_finalize(
    const float* __restrict__ ws, float* __restrict__ out)
{
    if (threadIdx.x == 0) {
        float mel_sum   = __hip_atomic_load(&ws[WS_MEL],   __ATOMIC_RELAXED, __HIP_MEMORY_SCOPE_AGENT);
        float gate_sum  = __hip_atomic_load(&ws[WS_GATE],  __ATOMIC_RELAXED, __HIP_MEMORY_SCOPE_AGENT);
        float align_sum = __hip_atomic_load(&ws[WS_ALIGN], __ATOMIC_RELAXED, __HIP_MEMORY_SCOPE_AGENT);
        float spk_sum   = __hip_atomic_load(&ws[WS_SPK],   __ATOMIC_RELAXED, __HIP_MEMORY_SCOPE_AGENT);
        float aug_sum   = __hip_atomic_load(&ws[WS_AUG],   __ATOMIC_RELAXED, __HIP_MEMORY_SCOPE_AGENT);

        float mel_loss  = mel_sum  * (1.0f / (float)N_MEL);
        float gate_loss = gate_sum * (1.0f / (float)N_GATE);
        float spk_loss  = spk_sum  * (1.0f / (float)BATCH);
        float aug_loss  = aug_sum  * (1.0f / (float)BATCH);
        float align_loss = fabsf(align_sum) * 0.0005f;
        float tmp = mel_loss + gate_loss;
        float total = 10.0f * tmp + 0.1f * (spk_loss + aug_loss) + align_loss;

        out[0] = total;
        out[1] = tmp;
        out[2] = spk_loss;
        out[3] = aug_loss;
        out[4] = align_loss;
    }
}

extern "C" void kernel_launch(void* const* d_in, const int* in_sizes, int n_in,
                              void* d_out, int out_size, void* d_ws, size_t ws_size,
                              hipStream_t stream) {
    const float* mel_out  = (const float*)d_in[0];
    const float* mel_post = (const float*)d_in[1];
    const float* gate_out = (const float*)d_in[2];
    const float* align    = (const float*)d_in[3];
    const float* spk_out  = (const float*)d_in[4];
    const float* aug_out  = (const float*)d_in[5];
    const float* mel_tgt  = (const float*)d_in[6];
    const float* gate_tgt = (const float*)d_in[7];
    const float* spk_tgt  = (const float*)d_in[8];
    const float* aug_tgt  = (const float*)d_in[9];
    // d_in[10] = step (unused by the loss values)

    float* ws = (float*)d_ws;
    float* out = (float*)d_out;

    // Zero accumulators (harness poisons ws with 0xAA)
    hipMemsetAsync(d_ws, 0, 80 * sizeof(float), stream);

    tacotron2_loss_reduce<<<dim3(GRID), dim3(BLOCK), 0, stream>>>(
        mel_out, mel_post, gate_out, align, spk_out, aug_out,
        mel_tgt, gate_tgt, spk_tgt, aug_tgt, ws);

    tacotron2_loss_finalize<<<dim3(1), dim3(64), 0, stream>>>(ws, out);
}

// Round 6
// 186.679 us; speedup vs baseline: 1.0751x; 1.0751x over previous
//
#include <hip/hip_runtime.h>
#include <hip/hip_bf16.h>

// Problem constants (from reference)
#define BATCH   64
#define NMEL    80
#define TFRAME  1000
#define NDEC    1000
#define TENC    200
#define NSPK    100
#define NAUG    10

// Element counts
#define N_MEL   (BATCH * NMEL * TFRAME)     // 5,120,000
#define N_GATE  (BATCH * TFRAME)            // 64,000
#define N_ALIGN (BATCH * NDEC * TENC)       // 12,800,000

// 4-element (16 B fp32) vector units
#define U_MEL   (N_MEL / 4)                 // 1,280,000
#define U_GATE  (N_GATE / 4)                // 16,000
#define U_ALIGN (N_ALIGN / 4)               // 3,200,000

#define BLOCK 256

// Section layout. R6: CE restructured to one WAVE per row with coalesced
// column access. R5 post-mortem: the single CE block (64 lanes scanning
// 400B-strided rows, 3 serial passes, scattered 64-cacheline gathers, cold)
// was a ~65 us single-wave serial tail — main sections drain in <5 us.
#define MEL_NB   2500                        // 512 units/block  (2 float4/lane x 3 streams)
#define ALIGN_NB 3125                        // 1024 units/block (4 float4/lane)
#define GATE_NB  16                          // 1024 units/block, bounds-checked
#define SPK_NB   16                          // 4 waves/block x 16 = 64 rows
#define AUG_NB   16                          // 4 waves/block x 16 = 64 rows
#define MEL_B0   0
#define ALIGN_B0 (MEL_B0 + MEL_NB)           // 2500
#define GATE_B0  (ALIGN_B0 + ALIGN_NB)       // 5625
#define SPK_B0   (GATE_B0 + GATE_NB)         // 5641
#define AUG_B0   (SPK_B0 + SPK_NB)           // 5657
#define GRID     (AUG_B0 + AUG_NB)           // 5673

// ws layout (floats), 64 B spacing per atomic target:
#define WS_MEL   0
#define WS_GATE  16
#define WS_ALIGN 32
#define WS_SPK   48
#define WS_AUG   64

__device__ __forceinline__ float waveReduceSum(float v) {
#pragma unroll
    for (int o = 32; o > 0; o >>= 1) v += __shfl_down(v, o, 64);
    return v;
}

// Butterfly all-reduce: every lane ends with the result.
__device__ __forceinline__ float waveAllReduceSum(float v) {
#pragma unroll
    for (int o = 1; o < 64; o <<= 1) v += __shfl_xor(v, o, 64);
    return v;
}
__device__ __forceinline__ float waveAllReduceMax(float v) {
#pragma unroll
    for (int o = 1; o < 64; o <<= 1) v = fmaxf(v, __shfl_xor(v, o, 64));
    return v;
}
// First-occurrence argmax (matches jnp.argmax tie-breaking).
__device__ __forceinline__ void waveAllReduceArgMax(float& v, int& i) {
#pragma unroll
    for (int o = 1; o < 64; o <<= 1) {
        float ov = __shfl_xor(v, o, 64);
        int   oi = __shfl_xor(i, o, 64);
        if (ov > v || (ov == v && oi < i)) { v = ov; i = oi; }
    }
}

// Native fp32 atomic add (global_atomic_add_f32); cross-XCD correct (R3-R5,
// absmax 0.0). Fire-and-forget: no return value -> no wait in the hot path.
__device__ __forceinline__ void fatomic_add(float* p, float v) {
    unsafeAtomicAdd(p, v);
}

__device__ __forceinline__ void blockReduceAtomic(float v, float* target) {
    __shared__ float smem[4];
    const int lane = threadIdx.x & 63;
    const int wid = threadIdx.x >> 6;
    v = waveReduceSum(v);
    if (lane == 0) smem[wid] = v;
    __syncthreads();
    if (threadIdx.x == 0) {
        fatomic_add(target, smem[0] + smem[1] + smem[2] + smem[3]);
    }
}

__global__ __launch_bounds__(BLOCK) void tacotron2_loss_reduce(
    const float* __restrict__ mel_out,
    const float* __restrict__ mel_post,
    const float* __restrict__ gate_out,
    const float* __restrict__ align,
    const float* __restrict__ spk_out,
    const float* __restrict__ aug_out,
    const float* __restrict__ mel_tgt,
    const float* __restrict__ gate_tgt,
    const float* __restrict__ spk_tgt,
    const float* __restrict__ aug_tgt,
    float* __restrict__ ws)
{
    const int bid = blockIdx.x;
    const int t = threadIdx.x;

    if (bid < ALIGN_B0) {
        // ---- MEL section: straight-line, 6 float4 loads issued up front ----
        const int base = bid * 512 + t;              // float4-unit index
        const float4* ao = (const float4*)mel_out;
        const float4* po = (const float4*)mel_post;
        const float4* to = (const float4*)mel_tgt;
        float4 a0 = ao[base], a1 = ao[base + 256];
        float4 p0 = po[base], p1 = po[base + 256];
        float4 t0 = to[base], t1 = to[base + 256];
        float s = 0.f, d;
        d = a0.x - t0.x; s = fmaf(d, d, s);
        d = a0.y - t0.y; s = fmaf(d, d, s);
        d = a0.z - t0.z; s = fmaf(d, d, s);
        d = a0.w - t0.w; s = fmaf(d, d, s);
        d = p0.x - t0.x; s = fmaf(d, d, s);
        d = p0.y - t0.y; s = fmaf(d, d, s);
        d = p0.z - t0.z; s = fmaf(d, d, s);
        d = p0.w - t0.w; s = fmaf(d, d, s);
        d = a1.x - t1.x; s = fmaf(d, d, s);
        d = a1.y - t1.y; s = fmaf(d, d, s);
        d = a1.z - t1.z; s = fmaf(d, d, s);
        d = a1.w - t1.w; s = fmaf(d, d, s);
        d = p1.x - t1.x; s = fmaf(d, d, s);
        d = p1.y - t1.y; s = fmaf(d, d, s);
        d = p1.z - t1.z; s = fmaf(d, d, s);
        d = p1.w - t1.w; s = fmaf(d, d, s);
        blockReduceAtomic(s, &ws[WS_MEL]);
    } else if (bid < GATE_B0) {
        // ---- ALIGN section: 4 float4 loads up front ----
        const int b = bid - ALIGN_B0;
        const int base = b * 1024 + t;               // float4-unit index
        const float4* av = (const float4*)align;
        float4 A0 = av[base];
        float4 A1 = av[base + 256];
        float4 A2 = av[base + 512];
        float4 A3 = av[base + 768];
        float s = 0.f;
        float4 regs[4] = {A0, A1, A2, A3};
#pragma unroll
        for (int k = 0; k < 4; k++) {
            const int u = base + 256 * k;            // unit; element e = 4u
            const int q = u / 50;                    // e / 200
            const int r = u - q * 50;                // (e % 200) / 4
            const float nf = (float)(q % NDEC) * (1.0f / (float)NDEC);
            const float tb = (float)(4 * r) * (1.0f / (float)TENC);
            const float fa[4] = {regs[k].x, regs[k].y, regs[k].z, regs[k].w};
#pragma unroll
            for (int j = 0; j < 4; j++) {
                float tf_ = tb + (float)j * (1.0f / (float)TENC);
                float d = nf - tf_;
                float g = 1.0f - __expf(d * d * -2.5f);   // 1/K_ALIGN = 2.5
                s = fmaf(fa[j], g, s);
            }
        }
        blockReduceAtomic(s, &ws[WS_ALIGN]);
    } else if (bid < SPK_B0) {
        // ---- GATE section: 4 predicated float4 loads ----
        const int b = bid - GATE_B0;
        const int base = b * 1024 + t;
        const float4* xo = (const float4*)gate_out;
        const float4* yo = (const float4*)gate_tgt;
        float s = 0.f;
#pragma unroll
        for (int k = 0; k < 4; k++) {
            const int u = base + 256 * k;
            if (u < U_GATE) {
                float4 x = xo[u];
                float4 y = yo[u];
                float fx[4] = {x.x, x.y, x.z, x.w};
                float fy[4] = {y.x, y.y, y.z, y.w};
#pragma unroll
                for (int j = 0; j < 4; j++) {
                    float xx = fx[j];
                    // softplus(x) = max(x,0) + log1p(exp(-|x|))
                    float sp = fmaxf(xx, 0.f) + log1pf(__expf(-fabsf(xx)));
                    s += sp - xx * fy[j];
                }
            }
        }
        blockReduceAtomic(s, &ws[WS_GATE]);
    } else if (bid < AUG_B0) {
        // ---- SPEAKER CE: one wave per row, coalesced columns ----
        const int lane = t & 63;
        const int row = (bid - SPK_B0) * 4 + (t >> 6);
        const float* xrow = spk_out + row * NSPK;
        const float* trow = spk_tgt + row * NSPK;
        const int c1 = lane + 64;
        const bool v1 = (c1 < NSPK);
        // Coalesced loads: lanes 0..63 read consecutive floats.
        float x0 = xrow[lane];
        float x1 = v1 ? xrow[c1] : -1e30f;
        float t0 = trow[lane];
        float t1 = v1 ? trow[c1] : -1e30f;

        float mx = waveAllReduceMax(fmaxf(x0, x1));
        float se = waveAllReduceSum(__expf(x0 - mx) + (v1 ? __expf(x1 - mx) : 0.f));
        // First-occurrence argmax of target; c0 < c1 so prefer t0 on ties.
        float bv = (t1 > t0) ? t1 : t0;
        int   bi = (t1 > t0) ? c1 : lane;
        waveAllReduceArgMax(bv, bi);
        float sel = ((lane == bi) ? x0 : 0.f) + ((v1 && c1 == bi) ? x1 : 0.f);
        float xlab = waveAllReduceSum(sel);
        if (lane == 0) {
            float loss = -(xlab - mx - __logf(se));
            fatomic_add(&ws[WS_SPK], loss);
        }
    } else {
        // ---- AUGMENT CE: one wave per row (10 cols in lanes 0..9) ----
        const int lane = t & 63;
        const int row = (bid - AUG_B0) * 4 + (t >> 6);
        const bool v0 = (lane < NAUG);
        const float* xrow = aug_out + row * NAUG;
        const float* trow = aug_tgt + row * NAUG;
        float x0 = v0 ? xrow[lane] : -1e30f;
        float t0 = v0 ? trow[lane] : -1e30f;

        float mx = waveAllReduceMax(x0);
        float se = waveAllReduceSum(v0 ? __expf(x0 - mx) : 0.f);
        float bv = t0; int bi = v0 ? lane : 0x7fffffff;
        waveAllReduceArgMax(bv, bi);
        float xlab = waveAllReduceSum((v0 && lane == bi) ? x0 : 0.f);
        if (lane == 0) {
            float loss = -(xlab - mx - __logf(se));
            fatomic_add(&ws[WS_AUG], loss);
        }
    }
}

// Kernel 2: finalize. One block; kernel boundary = release/acquire. Agent-scope
// atomic loads bypass (possibly stale) per-CU L1.
__global__ __launch_bounds__(64) void tacotron2_loss_finalize(
    const float* __restrict__ ws, float* __restrict__ out)
{
    if (threadIdx.x == 0) {
        float mel_sum   = __hip_atomic_load(&ws[WS_MEL],   __ATOMIC_RELAXED, __HIP_MEMORY_SCOPE_AGENT);
        float gate_sum  = __hip_atomic_load(&ws[WS_GATE],  __ATOMIC_RELAXED, __HIP_MEMORY_SCOPE_AGENT);
        float align_sum = __hip_atomic_load(&ws[WS_ALIGN], __ATOMIC_RELAXED, __HIP_MEMORY_SCOPE_AGENT);
        float spk_sum   = __hip_atomic_load(&ws[WS_SPK],   __ATOMIC_RELAXED, __HIP_MEMORY_SCOPE_AGENT);
        float aug_sum   = __hip_atomic_load(&ws[WS_AUG],   __ATOMIC_RELAXED, __HIP_MEMORY_SCOPE_AGENT);

        float mel_loss  = mel_sum  * (1.0f / (float)N_MEL);
        float gate_loss = gate_sum * (1.0f / (float)N_GATE);
        float spk_loss  = spk_sum  * (1.0f / (float)BATCH);
        float aug_loss  = aug_sum  * (1.0f / (float)BATCH);
        float align_loss = fabsf(align_sum) * 0.0005f;
        float tmp = mel_loss + gate_loss;
        float total = 10.0f * tmp + 0.1f * (spk_loss + aug_loss) + align_loss;

        out[0] = total;
        out[1] = tmp;
        out[2] = spk_loss;
        out[3] = aug_loss;
        out[4] = align_loss;
    }
}

extern "C" void kernel_launch(void* const* d_in, const int* in_sizes, int n_in,
                              void* d_out, int out_size, void* d_ws, size_t ws_size,
                              hipStream_t stream) {
    const float* mel_out  = (const float*)d_in[0];
    const float* mel_post = (const float*)d_in[1];
    const float* gate_out = (const float*)d_in[2];
    const float* align    = (const float*)d_in[3];
    const float* spk_out  = (const float*)d_in[4];
    const float* aug_out  = (const float*)d_in[5];
    const float* mel_tgt  = (const float*)d_in[6];
    const float* gate_tgt = (const float*)d_in[7];
    const float* spk_tgt  = (const float*)d_in[8];
    const float* aug_tgt  = (const float*)d_in[9];
    // d_in[10] = step (unused by the loss values)

    float* ws = (float*)d_ws;
    float* out = (float*)d_out;

    // Zero accumulators (harness poisons ws with 0xAA)
    hipMemsetAsync(d_ws, 0, 80 * sizeof(float), stream);

    tacotron2_loss_reduce<<<dim3(GRID), dim3(BLOCK), 0, stream>>>(
        mel_out, mel_post, gate_out, align, spk_out, aug_out,
        mel_tgt, gate_tgt, spk_tgt, aug_tgt, ws);

    tacotron2_loss_finalize<<<dim3(1), dim3(64), 0, stream>>>(ws, out);
}

// Round 7
// 156.509 us; speedup vs baseline: 1.2824x; 1.1928x over previous
//
#include <hip/hip_runtime.h>
#include <hip/hip_bf16.h>

// Problem constants (from reference)
#define BATCH   64
#define NMEL    80
#define TFRAME  1000
#define NDEC    1000
#define TENC    200
#define NSPK    100
#define NAUG    10

// Element counts
#define N_MEL   (BATCH * NMEL * TFRAME)     // 5,120,000
#define N_GATE  (BATCH * TFRAME)            // 64,000
#define N_ALIGN (BATCH * NDEC * TENC)       // 12,800,000

// 4-element (16 B fp32) vector units
#define U_MEL   (N_MEL / 4)                 // 1,280,000
#define U_GATE  (N_GATE / 4)                // 16,000
#define U_ALIGN (N_ALIGN / 4)               // 3,200,000

#define BLOCK 256

// Section layout (same work split as R6).
#define MEL_NB   2500                        // 512 units/block  (2 float4/lane x 3 streams)
#define ALIGN_NB 3125                        // 1024 units/block (4 float4/lane)
#define GATE_NB  16                         // 1024 units/block, bounds-checked
#define SPK_NB   16                         // 4 waves/block x 16 = 64 rows
#define AUG_NB   16                         // 4 waves/block x 16 = 64 rows
#define MEL_B0   0
#define ALIGN_B0 (MEL_B0 + MEL_NB)          // 2500
#define GATE_B0  (ALIGN_B0 + ALIGN_NB)      // 5625
#define SPK_B0   (GATE_B0 + GATE_NB)        // 5641
#define AUG_B0   (SPK_B0 + SPK_NB)          // 5657
#define GRID     (AUG_B0 + AUG_NB)          // 5673

// R7: ZERO atomics in the hot path. R4-R6 all plateaued at 66-70 us with
// ~6k same-address device-scope atomics in common; avg wave lifetime ~12 us
// (occupancy integral) says waves were parked waiting on the serialized
// atomic queue (~11 ns/atomic x 6k = the whole kernel). Each block now
// plain-stores its partial to a DISTINCT slot; a 1-block finalize kernel
// reduces the ~5.8k partials. No memset needed: every slot is written.
//
// Partial buffer layout in ws (floats):
#define P_MEL    0                           // 2500
#define P_ALIGN  (P_MEL + MEL_NB)            // 2500..5625
#define P_GATE   (P_ALIGN + ALIGN_NB)        // 5625..5641
#define P_SPK    (P_GATE + GATE_NB)          // 5641..5705 (64 rows)
#define P_AUG    (P_SPK + 64)                // 5705..5769 (64 rows)
#define P_TOTAL  (P_AUG + 64)                // 5769 floats = ~23 KB

__device__ __forceinline__ float waveReduceSum(float v) {
#pragma unroll
    for (int o = 32; o > 0; o >>= 1) v += __shfl_down(v, o, 64);
    return v;
}

// Butterfly all-reduce: every lane ends with the result.
__device__ __forceinline__ float waveAllReduceSum(float v) {
#pragma unroll
    for (int o = 1; o < 64; o <<= 1) v += __shfl_xor(v, o, 64);
    return v;
}
__device__ __forceinline__ float waveAllReduceMax(float v) {
#pragma unroll
    for (int o = 1; o < 64; o <<= 1) v = fmaxf(v, __shfl_xor(v, o, 64));
    return v;
}
// First-occurrence argmax (matches jnp.argmax tie-breaking).
__device__ __forceinline__ void waveAllReduceArgMax(float& v, int& i) {
#pragma unroll
    for (int o = 1; o < 64; o <<= 1) {
        float ov = __shfl_xor(v, o, 64);
        int   oi = __shfl_xor(i, o, 64);
        if (ov > v || (ov == v && oi < i)) { v = ov; i = oi; }
    }
}

// Block reduce -> ONE plain store to a distinct slot (no atomic, no RMW).
__device__ __forceinline__ void blockReduceStore(float v, float* slot) {
    __shared__ float smem[4];
    const int lane = threadIdx.x & 63;
    const int wid = threadIdx.x >> 6;
    v = waveReduceSum(v);
    if (lane == 0) smem[wid] = v;
    __syncthreads();
    if (threadIdx.x == 0) {
        *slot = smem[0] + smem[1] + smem[2] + smem[3];
    }
}

__global__ __launch_bounds__(BLOCK) void tacotron2_loss_reduce(
    const float* __restrict__ mel_out,
    const float* __restrict__ mel_post,
    const float* __restrict__ gate_out,
    const float* __restrict__ align,
    const float* __restrict__ spk_out,
    const float* __restrict__ aug_out,
    const float* __restrict__ mel_tgt,
    const float* __restrict__ gate_tgt,
    const float* __restrict__ spk_tgt,
    const float* __restrict__ aug_tgt,
    float* __restrict__ ws)
{
    const int bid = blockIdx.x;
    const int t = threadIdx.x;

    if (bid < ALIGN_B0) {
        // ---- MEL section: straight-line, 6 float4 loads issued up front ----
        const int base = bid * 512 + t;              // float4-unit index
        const float4* ao = (const float4*)mel_out;
        const float4* po = (const float4*)mel_post;
        const float4* to = (const float4*)mel_tgt;
        float4 a0 = ao[base], a1 = ao[base + 256];
        float4 p0 = po[base], p1 = po[base + 256];
        float4 t0 = to[base], t1 = to[base + 256];
        float s = 0.f, d;
        d = a0.x - t0.x; s = fmaf(d, d, s);
        d = a0.y - t0.y; s = fmaf(d, d, s);
        d = a0.z - t0.z; s = fmaf(d, d, s);
        d = a0.w - t0.w; s = fmaf(d, d, s);
        d = p0.x - t0.x; s = fmaf(d, d, s);
        d = p0.y - t0.y; s = fmaf(d, d, s);
        d = p0.z - t0.z; s = fmaf(d, d, s);
        d = p0.w - t0.w; s = fmaf(d, d, s);
        d = a1.x - t1.x; s = fmaf(d, d, s);
        d = a1.y - t1.y; s = fmaf(d, d, s);
        d = a1.z - t1.z; s = fmaf(d, d, s);
        d = a1.w - t1.w; s = fmaf(d, d, s);
        d = p1.x - t1.x; s = fmaf(d, d, s);
        d = p1.y - t1.y; s = fmaf(d, d, s);
        d = p1.z - t1.z; s = fmaf(d, d, s);
        d = p1.w - t1.w; s = fmaf(d, d, s);
        blockReduceStore(s, &ws[P_MEL + bid]);
    } else if (bid < GATE_B0) {
        // ---- ALIGN section: 4 float4 loads up front ----
        const int b = bid - ALIGN_B0;
        const int base = b * 1024 + t;               // float4-unit index
        const float4* av = (const float4*)align;
        float4 A0 = av[base];
        float4 A1 = av[base + 256];
        float4 A2 = av[base + 512];
        float4 A3 = av[base + 768];
        float s = 0.f;
        float4 regs[4] = {A0, A1, A2, A3};
#pragma unroll
        for (int k = 0; k < 4; k++) {
            const int u = base + 256 * k;            // unit; element e = 4u
            const int q = u / 50;                    // e / 200
            const int r = u - q * 50;                // (e % 200) / 4
            const float nf = (float)(q % NDEC) * (1.0f / (float)NDEC);
            const float tb = (float)(4 * r) * (1.0f / (float)TENC);
            const float fa[4] = {regs[k].x, regs[k].y, regs[k].z, regs[k].w};
#pragma unroll
            for (int j = 0; j < 4; j++) {
                float tf_ = tb + (float)j * (1.0f / (float)TENC);
                float d = nf - tf_;
                float g = 1.0f - __expf(d * d * -2.5f);   // 1/K_ALIGN = 2.5
                s = fmaf(fa[j], g, s);
            }
        }
        blockReduceStore(s, &ws[P_ALIGN + b]);
    } else if (bid < SPK_B0) {
        // ---- GATE section: 4 predicated float4 loads ----
        const int b = bid - GATE_B0;
        const int base = b * 1024 + t;
        const float4* xo = (const float4*)gate_out;
        const float4* yo = (const float4*)gate_tgt;
        float s = 0.f;
#pragma unroll
        for (int k = 0; k < 4; k++) {
            const int u = base + 256 * k;
            if (u < U_GATE) {
                float4 x = xo[u];
                float4 y = yo[u];
                float fx[4] = {x.x, x.y, x.z, x.w};
                float fy[4] = {y.x, y.y, y.z, y.w};
#pragma unroll
                for (int j = 0; j < 4; j++) {
                    float xx = fx[j];
                    // softplus(x) = max(x,0) + log1p(exp(-|x|))
                    float sp = fmaxf(xx, 0.f) + log1pf(__expf(-fabsf(xx)));
                    s += sp - xx * fy[j];
                }
            }
        }
        blockReduceStore(s, &ws[P_GATE + b]);
    } else if (bid < AUG_B0) {
        // ---- SPEAKER CE: one wave per row, coalesced columns ----
        const int lane = t & 63;
        const int row = (bid - SPK_B0) * 4 + (t >> 6);
        const float* xrow = spk_out + row * NSPK;
        const float* trow = spk_tgt + row * NSPK;
        const int c1 = lane + 64;
        const bool v1 = (c1 < NSPK);
        float x0 = xrow[lane];
        float x1 = v1 ? xrow[c1] : -1e30f;
        float t0 = trow[lane];
        float t1 = v1 ? trow[c1] : -1e30f;

        float mx = waveAllReduceMax(fmaxf(x0, x1));
        float se = waveAllReduceSum(__expf(x0 - mx) + (v1 ? __expf(x1 - mx) : 0.f));
        float bv = (t1 > t0) ? t1 : t0;
        int   bi = (t1 > t0) ? c1 : lane;
        waveAllReduceArgMax(bv, bi);
        float sel = ((lane == bi) ? x0 : 0.f) + ((v1 && c1 == bi) ? x1 : 0.f);
        float xlab = waveAllReduceSum(sel);
        if (lane == 0) {
            ws[P_SPK + row] = -(xlab - mx - __logf(se));   // distinct slot per row
        }
    } else {
        // ---- AUGMENT CE: one wave per row (10 cols in lanes 0..9) ----
        const int lane = t & 63;
        const int row = (bid - AUG_B0) * 4 + (t >> 6);
        const bool v0 = (lane < NAUG);
        const float* xrow = aug_out + row * NAUG;
        const float* trow = aug_tgt + row * NAUG;
        float x0 = v0 ? xrow[lane] : -1e30f;
        float t0 = v0 ? trow[lane] : -1e30f;

        float mx = waveAllReduceMax(x0);
        float se = waveAllReduceSum(v0 ? __expf(x0 - mx) : 0.f);
        float bv = t0; int bi = v0 ? lane : 0x7fffffff;
        waveAllReduceArgMax(bv, bi);
        float xlab = waveAllReduceSum((v0 && lane == bi) ? x0 : 0.f);
        if (lane == 0) {
            ws[P_AUG + row] = -(xlab - mx - __logf(se));   // distinct slot per row
        }
    }
}

// Kernel 2: finalize. One block reduces the ~5.8k partials (23 KB, L2/L3-hot
// after the kernel-end flush) and writes the 5 outputs. Kernel boundary
// provides visibility of kernel-1 stores.
__global__ __launch_bounds__(BLOCK) void tacotron2_loss_finalize(
    const float* __restrict__ ws, float* __restrict__ out)
{
    const int t = threadIdx.x;
    float s_mel = 0.f, s_align = 0.f, s_gate = 0.f, s_spk = 0.f, s_aug = 0.f;

    for (int i = t; i < MEL_NB; i += BLOCK)   s_mel   += ws[P_MEL + i];
    for (int i = t; i < ALIGN_NB; i += BLOCK) s_align += ws[P_ALIGN + i];
    if (t < GATE_NB) s_gate = ws[P_GATE + t];
    if (t < 64)      s_spk  = ws[P_SPK + t];
    if (t < 64)      s_aug  = ws[P_AUG + t];

    __shared__ float smem[5][4];
    const int lane = t & 63;
    const int wid = t >> 6;
    s_mel   = waveReduceSum(s_mel);
    s_align = waveReduceSum(s_align);
    s_gate  = waveReduceSum(s_gate);
    s_spk   = waveReduceSum(s_spk);
    s_aug   = waveReduceSum(s_aug);
    if (lane == 0) {
        smem[0][wid] = s_mel;
        smem[1][wid] = s_align;
        smem[2][wid] = s_gate;
        smem[3][wid] = s_spk;
        smem[4][wid] = s_aug;
    }
    __syncthreads();

    if (t == 0) {
        float mel_sum   = smem[0][0] + smem[0][1] + smem[0][2] + smem[0][3];
        float align_sum = smem[1][0] + smem[1][1] + smem[1][2] + smem[1][3];
        float gate_sum  = smem[2][0] + smem[2][1] + smem[2][2] + smem[2][3];
        float spk_sum   = smem[3][0] + smem[3][1] + smem[3][2] + smem[3][3];
        float aug_sum   = smem[4][0] + smem[4][1] + smem[4][2] + smem[4][3];

        float mel_loss  = mel_sum  * (1.0f / (float)N_MEL);
        float gate_loss = gate_sum * (1.0f / (float)N_GATE);
        float spk_loss  = spk_sum  * (1.0f / (float)BATCH);
        float aug_loss  = aug_sum  * (1.0f / (float)BATCH);
        float align_loss = fabsf(align_sum) * 0.0005f;
        float tmp = mel_loss + gate_loss;
        float total = 10.0f * tmp + 0.1f * (spk_loss + aug_loss) + align_loss;

        out[0] = total;
        out[1] = tmp;
        out[2] = spk_loss;
        out[3] = aug_loss;
        out[4] = align_loss;
    }
}

extern "C" void kernel_launch(void* const* d_in, const int* in_sizes, int n_in,
                              void* d_out, int out_size, void* d_ws, size_t ws_size,
                              hipStream_t stream) {
    const float* mel_out  = (const float*)d_in[0];
    const float* mel_post = (const float*)d_in[1];
    const float* gate_out = (const float*)d_in[2];
    const float* align    = (const float*)d_in[3];
    const float* spk_out  = (const float*)d_in[4];
    const float* aug_out  = (const float*)d_in[5];
    const float* mel_tgt  = (const float*)d_in[6];
    const float* gate_tgt = (const float*)d_in[7];
    const float* spk_tgt  = (const float*)d_in[8];
    const float* aug_tgt  = (const float*)d_in[9];
    // d_in[10] = step (unused by the loss values)

    float* ws = (float*)d_ws;
    float* out = (float*)d_out;

    // No memset needed: every partial slot is unconditionally written by
    // the reduce kernel before finalize reads it.

    tacotron2_loss_reduce<<<dim3(GRID), dim3(BLOCK), 0, stream>>>(
        mel_out, mel_post, gate_out, align, spk_out, aug_out,
        mel_tgt, gate_tgt, spk_tgt, aug_tgt, ws);

    tacotron2_loss_finalize<<<dim3(1), dim3(BLOCK), 0, stream>>>(ws, out);
}

// Round 8
// 153.030 us; speedup vs baseline: 1.3116x; 1.0227x over previous
//
#include <hip/hip_runtime.h>
#include <hip/hip_bf16.h>

// Problem constants (from reference)
#define BATCH   64
#define NMEL    80
#define TFRAME  1000
#define NDEC    1000
#define TENC    200
#define NSPK    100
#define NAUG    10

// Element counts
#define N_MEL   (BATCH * NMEL * TFRAME)     // 5,120,000
#define N_GATE  (BATCH * TFRAME)            // 64,000
#define N_ALIGN (BATCH * NDEC * TENC)       // 12,800,000

// 4-element (16 B fp32) vector units
#define U_MEL   (N_MEL / 4)                 // 1,280,000
#define U_GATE  (N_GATE / 4)                // 16,000
#define U_ALIGN (N_ALIGN / 4)               // 3,200,000

#define BLOCK 256

// R8: double per-block load batches (mel 12 loads = 192 B/lane in flight,
// align 8 loads = 128 B/lane) and halve block count 5673 -> 2861. R7 proved
// atomics were the plateau (reduce dropped below the 41 us ws-poison fill
// once they were gone); remaining gap to the ~18 us read floor is latency /
// block-recycle, addressed by more bytes in flight per wave.
#define MEL_NB     1250                      // 1024 units/block (4 float4/lane x 3 streams)
#define ALIGN_NB   1563                      // 1562 x 2048 units + 1 x 1024 tail
#define ALIGN_FULL 1562
#define GATE_NB    16                        // 1024 units/block, bounds-checked
#define SPK_NB     16                        // 4 waves/block x 16 = 64 rows
#define AUG_NB     16                        // 4 waves/block x 16 = 64 rows
#define MEL_B0     0
#define ALIGN_B0   (MEL_B0 + MEL_NB)         // 1250
#define GATE_B0    (ALIGN_B0 + ALIGN_NB)     // 2813
#define SPK_B0     (GATE_B0 + GATE_NB)       // 2829
#define AUG_B0     (SPK_B0 + SPK_NB)         // 2845
#define GRID       (AUG_B0 + AUG_NB)         // 2861

// Partial buffer layout in ws (floats). Zero atomics anywhere; every slot is
// unconditionally written each launch (no memset needed).
#define P_MEL    0                           // 1250
#define P_ALIGN  (P_MEL + MEL_NB)            // 1250..2813
#define P_GATE   (P_ALIGN + ALIGN_NB)        // 2813..2829
#define P_SPK    (P_GATE + GATE_NB)          // 2829..2893 (64 rows)
#define P_AUG    (P_SPK + 64)                // 2893..2957 (64 rows)

__device__ __forceinline__ float waveReduceSum(float v) {
#pragma unroll
    for (int o = 32; o > 0; o >>= 1) v += __shfl_down(v, o, 64);
    return v;
}

// Butterfly all-reduce: every lane ends with the result.
__device__ __forceinline__ float waveAllReduceSum(float v) {
#pragma unroll
    for (int o = 1; o < 64; o <<= 1) v += __shfl_xor(v, o, 64);
    return v;
}
__device__ __forceinline__ float waveAllReduceMax(float v) {
#pragma unroll
    for (int o = 1; o < 64; o <<= 1) v = fmaxf(v, __shfl_xor(v, o, 64));
    return v;
}
// First-occurrence argmax (matches jnp.argmax tie-breaking).
__device__ __forceinline__ void waveAllReduceArgMax(float& v, int& i) {
#pragma unroll
    for (int o = 1; o < 64; o <<= 1) {
        float ov = __shfl_xor(v, o, 64);
        int   oi = __shfl_xor(i, o, 64);
        if (ov > v || (ov == v && oi < i)) { v = ov; i = oi; }
    }
}

// Block reduce -> ONE plain store to a distinct slot (no atomic, no RMW).
__device__ __forceinline__ void blockReduceStore(float v, float* slot) {
    __shared__ float smem[4];
    const int lane = threadIdx.x & 63;
    const int wid = threadIdx.x >> 6;
    v = waveReduceSum(v);
    if (lane == 0) smem[wid] = v;
    __syncthreads();
    if (threadIdx.x == 0) {
        *slot = smem[0] + smem[1] + smem[2] + smem[3];
    }
}

// Alignment penalty contribution for float4 unit u (element e = 4u).
__device__ __forceinline__ float alignContrib(int u, float4 v) {
    const int q = u / 50;                    // e / 200
    const int r = u - q * 50;                // (e % 200) / 4
    const float nf = (float)(q % NDEC) * (1.0f / (float)NDEC);
    const float tb = (float)(4 * r) * (1.0f / (float)TENC);
    const float fa[4] = {v.x, v.y, v.z, v.w};
    float s = 0.f;
#pragma unroll
    for (int j = 0; j < 4; j++) {
        float d = nf - (tb + (float)j * (1.0f / (float)TENC));
        float g = 1.0f - __expf(d * d * -2.5f);   // 1/K_ALIGN = 2.5
        s = fmaf(fa[j], g, s);
    }
    return s;
}

__global__ __launch_bounds__(BLOCK) void tacotron2_loss_reduce(
    const float* __restrict__ mel_out,
    const float* __restrict__ mel_post,
    const float* __restrict__ gate_out,
    const float* __restrict__ align,
    const float* __restrict__ spk_out,
    const float* __restrict__ aug_out,
    const float* __restrict__ mel_tgt,
    const float* __restrict__ gate_tgt,
    const float* __restrict__ spk_tgt,
    const float* __restrict__ aug_tgt,
    float* __restrict__ ws)
{
    const int bid = blockIdx.x;
    const int t = threadIdx.x;

    if (bid < ALIGN_B0) {
        // ---- MEL: 1024 units/block, 12 float4 loads issued up front ----
        const int base = bid * 1024 + t;             // float4-unit index
        const float4* ao = (const float4*)mel_out;
        const float4* po = (const float4*)mel_post;
        const float4* to = (const float4*)mel_tgt;
        float4 a[4], p[4], tt[4];
#pragma unroll
        for (int k = 0; k < 4; k++) a[k]  = ao[base + 256 * k];
#pragma unroll
        for (int k = 0; k < 4; k++) p[k]  = po[base + 256 * k];
#pragma unroll
        for (int k = 0; k < 4; k++) tt[k] = to[base + 256 * k];
        float s0 = 0.f, s1 = 0.f, d;
#pragma unroll
        for (int k = 0; k < 4; k++) {
            d = a[k].x - tt[k].x; s0 = fmaf(d, d, s0);
            d = a[k].y - tt[k].y; s1 = fmaf(d, d, s1);
            d = a[k].z - tt[k].z; s0 = fmaf(d, d, s0);
            d = a[k].w - tt[k].w; s1 = fmaf(d, d, s1);
            d = p[k].x - tt[k].x; s0 = fmaf(d, d, s0);
            d = p[k].y - tt[k].y; s1 = fmaf(d, d, s1);
            d = p[k].z - tt[k].z; s0 = fmaf(d, d, s0);
            d = p[k].w - tt[k].w; s1 = fmaf(d, d, s1);
        }
        blockReduceStore(s0 + s1, &ws[P_MEL + bid]);
    } else if (bid < GATE_B0) {
        // ---- ALIGN: 2048 units/block (8 loads), 1024-unit tail block ----
        const int b = bid - ALIGN_B0;
        const float4* av = (const float4*)align;
        float s = 0.f;
        if (b < ALIGN_FULL) {
            const int base = b * 2048 + t;
            float4 r[8];
#pragma unroll
            for (int k = 0; k < 8; k++) r[k] = av[base + 256 * k];
#pragma unroll
            for (int k = 0; k < 8; k++) s += alignContrib(base + 256 * k, r[k]);
        } else {
            const int base = ALIGN_FULL * 2048 + t;  // last 1024 units exactly
            float4 r[4];
#pragma unroll
            for (int k = 0; k < 4; k++) r[k] = av[base + 256 * k];
#pragma unroll
            for (int k = 0; k < 4; k++) s += alignContrib(base + 256 * k, r[k]);
        }
        blockReduceStore(s, &ws[P_ALIGN + b]);
    } else if (bid < SPK_B0) {
        // ---- GATE: 4 predicated float4 loads ----
        const int b = bid - GATE_B0;
        const int base = b * 1024 + t;
        const float4* xo = (const float4*)gate_out;
        const float4* yo = (const float4*)gate_tgt;
        float s = 0.f;
#pragma unroll
        for (int k = 0; k < 4; k++) {
            const int u = base + 256 * k;
            if (u < U_GATE) {
                float4 x = xo[u];
                float4 y = yo[u];
                float fx[4] = {x.x, x.y, x.z, x.w};
                float fy[4] = {y.x, y.y, y.z, y.w};
#pragma unroll
                for (int j = 0; j < 4; j++) {
                    float xx = fx[j];
                    // softplus(x) = max(x,0) + log1p(exp(-|x|))
                    float sp = fmaxf(xx, 0.f) + log1pf(__expf(-fabsf(xx)));
                    s += sp - xx * fy[j];
                }
            }
        }
        blockReduceStore(s, &ws[P_GATE + b]);
    } else if (bid < AUG_B0) {
        // ---- SPEAKER CE: one wave per row, coalesced columns ----
        const int lane = t & 63;
        const int row = (bid - SPK_B0) * 4 + (t >> 6);
        const float* xrow = spk_out + row * NSPK;
        const float* trow = spk_tgt + row * NSPK;
        const int c1 = lane + 64;
        const bool v1 = (c1 < NSPK);
        float x0 = xrow[lane];
        float x1 = v1 ? xrow[c1] : -1e30f;
        float t0 = trow[lane];
        float t1 = v1 ? trow[c1] : -1e30f;

        float mx = waveAllReduceMax(fmaxf(x0, x1));
        float se = waveAllReduceSum(__expf(x0 - mx) + (v1 ? __expf(x1 - mx) : 0.f));
        float bv = (t1 > t0) ? t1 : t0;
        int   bi = (t1 > t0) ? c1 : lane;
        waveAllReduceArgMax(bv, bi);
        float sel = ((lane == bi) ? x0 : 0.f) + ((v1 && c1 == bi) ? x1 : 0.f);
        float xlab = waveAllReduceSum(sel);
        if (lane == 0) {
            ws[P_SPK + row] = -(xlab - mx - __logf(se));   // distinct slot per row
        }
    } else {
        // ---- AUGMENT CE: one wave per row (10 cols in lanes 0..9) ----
        const int lane = t & 63;
        const int row = (bid - AUG_B0) * 4 + (t >> 6);
        const bool v0 = (lane < NAUG);
        const float* xrow = aug_out + row * NAUG;
        const float* trow = aug_tgt + row * NAUG;
        float x0 = v0 ? xrow[lane] : -1e30f;
        float t0 = v0 ? trow[lane] : -1e30f;

        float mx = waveAllReduceMax(x0);
        float se = waveAllReduceSum(v0 ? __expf(x0 - mx) : 0.f);
        float bv = t0; int bi = v0 ? lane : 0x7fffffff;
        waveAllReduceArgMax(bv, bi);
        float xlab = waveAllReduceSum((v0 && lane == bi) ? x0 : 0.f);
        if (lane == 0) {
            ws[P_AUG + row] = -(xlab - mx - __logf(se));   // distinct slot per row
        }
    }
}

// Kernel 2: finalize. One block reduces the ~2.9k partials (12 KB, L2/L3-hot)
// and writes the 5 outputs. Kernel boundary provides visibility of k1 stores.
__global__ __launch_bounds__(BLOCK) void tacotron2_loss_finalize(
    const float* __restrict__ ws, float* __restrict__ out)
{
    const int t = threadIdx.x;
    float s_mel = 0.f, s_align = 0.f, s_gate = 0.f, s_spk = 0.f, s_aug = 0.f;

    for (int i = t; i < MEL_NB; i += BLOCK)   s_mel   += ws[P_MEL + i];
    for (int i = t; i < ALIGN_NB; i += BLOCK) s_align += ws[P_ALIGN + i];
    if (t < GATE_NB) s_gate = ws[P_GATE + t];
    if (t < 64)      s_spk  = ws[P_SPK + t];
    if (t < 64)      s_aug  = ws[P_AUG + t];

    __shared__ float smem[5][4];
    const int lane = t & 63;
    const int wid = t >> 6;
    s_mel   = waveReduceSum(s_mel);
    s_align = waveReduceSum(s_align);
    s_gate  = waveReduceSum(s_gate);
    s_spk   = waveReduceSum(s_spk);
    s_aug   = waveReduceSum(s_aug);
    if (lane == 0) {
        smem[0][wid] = s_mel;
        smem[1][wid] = s_align;
        smem[2][wid] = s_gate;
        smem[3][wid] = s_spk;
        smem[4][wid] = s_aug;
    }
    __syncthreads();

    if (t == 0) {
        float mel_sum   = smem[0][0] + smem[0][1] + smem[0][2] + smem[0][3];
        float align_sum = smem[1][0] + smem[1][1] + smem[1][2] + smem[1][3];
        float gate_sum  = smem[2][0] + smem[2][1] + smem[2][2] + smem[2][3];
        float spk_sum   = smem[3][0] + smem[3][1] + smem[3][2] + smem[3][3];
        float aug_sum   = smem[4][0] + smem[4][1] + smem[4][2] + smem[4][3];

        float mel_loss  = mel_sum  * (1.0f / (float)N_MEL);
        float gate_loss = gate_sum * (1.0f / (float)N_GATE);
        float spk_loss  = spk_sum  * (1.0f / (float)BATCH);
        float aug_loss  = aug_sum  * (1.0f / (float)BATCH);
        float align_loss = fabsf(align_sum) * 0.0005f;
        float tmp = mel_loss + gate_loss;
        float total = 10.0f * tmp + 0.1f * (spk_loss + aug_loss) + align_loss;

        out[0] = total;
        out[1] = tmp;
        out[2] = spk_loss;
        out[3] = aug_loss;
        out[4] = align_loss;
    }
}

extern "C" void kernel_launch(void* const* d_in, const int* in_sizes, int n_in,
                              void* d_out, int out_size, void* d_ws, size_t ws_size,
                              hipStream_t stream) {
    const float* mel_out  = (const float*)d_in[0];
    const float* mel_post = (const float*)d_in[1];
    const float* gate_out = (const float*)d_in[2];
    const float* align    = (const float*)d_in[3];
    const float* spk_out  = (const float*)d_in[4];
    const float* aug_out  = (const float*)d_in[5];
    const float* mel_tgt  = (const float*)d_in[6];
    const float* gate_tgt = (const float*)d_in[7];
    const float* spk_tgt  = (const float*)d_in[8];
    const float* aug_tgt  = (const float*)d_in[9];
    // d_in[10] = step (unused by the loss values)

    float* ws = (float*)d_ws;
    float* out = (float*)d_out;

    tacotron2_loss_reduce<<<dim3(GRID), dim3(BLOCK), 0, stream>>>(
        mel_out, mel_post, gate_out, align, spk_out, aug_out,
        mel_tgt, gate_tgt, spk_tgt, aug_tgt, ws);

    tacotron2_loss_finalize<<<dim3(1), dim3(BLOCK), 0, stream>>>(ws, out);
}

// Round 10
// 152.196 us; speedup vs baseline: 1.3187x; 1.0055x over previous
//
#include <hip/hip_runtime.h>
#include <hip/hip_bf16.h>

// Problem constants (from reference)
#define BATCH   64
#define NMEL    80
#define TFRAME  1000
#define NDEC    1000
#define TENC    200
#define NSPK    100
#define NAUG    10

// Element counts
#define N_MEL   (BATCH * NMEL * TFRAME)     // 5,120,000
#define N_GATE  (BATCH * TFRAME)            // 64,000
#define N_ALIGN (BATCH * NDEC * TENC)       // 12,800,000

// 4-element (16 B fp32) vector units
#define U_MEL   (N_MEL / 4)                 // 1,280,000
#define U_GATE  (N_GATE / 4)                // 16,000
#define U_ALIGN (N_ALIGN / 4)               // 3,200,000

#define BLOCK 256

// R10 = R9 with the nontemporal-load type fixed (clang ext_vector instead of
// HIP_vector_type — __builtin_nontemporal_load requires scalar/ext-vector).
// Single machine-resident block round: 1830 blocks (~7/CU co-resident),
// mel 1280 units/block (15 float4 loads/lane = 240 B in flight), align
// 4096 units/block (16 loads = 256 B). Streams use nontemporal loads.
#define MEL_NB     1000                      // 1280 units/block (5 float4/lane x 3 streams)
#define ALIGN_NB   782                       // 781 x 4096 units + 1 x 1024 tail
#define ALIGN_FULL 781
#define GATE_NB    16                        // 1024 units/block, bounds-checked
#define SPK_NB     16                        // 4 waves/block x 16 = 64 rows
#define AUG_NB     16                        // 4 waves/block x 16 = 64 rows
#define MEL_B0     0
#define ALIGN_B0   (MEL_B0 + MEL_NB)         // 1000
#define GATE_B0    (ALIGN_B0 + ALIGN_NB)     // 1782
#define SPK_B0     (GATE_B0 + GATE_NB)       // 1798
#define AUG_B0     (SPK_B0 + SPK_NB)         // 1814
#define GRID       (AUG_B0 + AUG_NB)         // 1830

// Partial buffer layout in ws (floats). Zero atomics anywhere; every slot is
// unconditionally written each launch (no memset needed).
#define P_MEL    0                           // 1000
#define P_ALIGN  (P_MEL + MEL_NB)            // 1000..1782
#define P_GATE   (P_ALIGN + ALIGN_NB)        // 1782..1798
#define P_SPK    (P_GATE + GATE_NB)          // 1798..1862 (64 rows)
#define P_AUG    (P_SPK + 64)                // 1862..1926 (64 rows)

// Clang ext-vector float4 (accepted by __builtin_nontemporal_load).
typedef float vfloat4 __attribute__((ext_vector_type(4)));

__device__ __forceinline__ float waveReduceSum(float v) {
#pragma unroll
    for (int o = 32; o > 0; o >>= 1) v += __shfl_down(v, o, 64);
    return v;
}

// Butterfly all-reduce: every lane ends with the result.
__device__ __forceinline__ float waveAllReduceSum(float v) {
#pragma unroll
    for (int o = 1; o < 64; o <<= 1) v += __shfl_xor(v, o, 64);
    return v;
}
__device__ __forceinline__ float waveAllReduceMax(float v) {
#pragma unroll
    for (int o = 1; o < 64; o <<= 1) v = fmaxf(v, __shfl_xor(v, o, 64));
    return v;
}
// First-occurrence argmax (matches jnp.argmax tie-breaking).
__device__ __forceinline__ void waveAllReduceArgMax(float& v, int& i) {
#pragma unroll
    for (int o = 1; o < 64; o <<= 1) {
        float ov = __shfl_xor(v, o, 64);
        int   oi = __shfl_xor(i, o, 64);
        if (ov > v || (ov == v && oi < i)) { v = ov; i = oi; }
    }
}

// Block reduce -> ONE plain store to a distinct slot (no atomic, no RMW).
__device__ __forceinline__ void blockReduceStore(float v, float* slot) {
    __shared__ float smem[4];
    const int lane = threadIdx.x & 63;
    const int wid = threadIdx.x >> 6;
    v = waveReduceSum(v);
    if (lane == 0) smem[wid] = v;
    __syncthreads();
    if (threadIdx.x == 0) {
        *slot = smem[0] + smem[1] + smem[2] + smem[3];
    }
}

// Nontemporal float4 load (single-use streaming data; early L2/L3 evict).
__device__ __forceinline__ vfloat4 ntload(const float* p) {
    return __builtin_nontemporal_load((const vfloat4*)p);
}

// Alignment penalty contribution for float4 unit u (element e = 4u).
__device__ __forceinline__ float alignContrib(int u, vfloat4 v) {
    const int q = u / 50;                    // e / 200
    const int r = u - q * 50;                // (e % 200) / 4
    const float nf = (float)(q % NDEC) * (1.0f / (float)NDEC);
    const float tb = (float)(4 * r) * (1.0f / (float)TENC);
    float s = 0.f;
#pragma unroll
    for (int j = 0; j < 4; j++) {
        float d = nf - (tb + (float)j * (1.0f / (float)TENC));
        float g = 1.0f - __expf(d * d * -2.5f);   // 1/K_ALIGN = 2.5
        s = fmaf(v[j], g, s);
    }
    return s;
}

__global__ __launch_bounds__(BLOCK) void tacotron2_loss_reduce(
    const float* __restrict__ mel_out,
    const float* __restrict__ mel_post,
    const float* __restrict__ gate_out,
    const float* __restrict__ align,
    const float* __restrict__ spk_out,
    const float* __restrict__ aug_out,
    const float* __restrict__ mel_tgt,
    const float* __restrict__ gate_tgt,
    const float* __restrict__ spk_tgt,
    const float* __restrict__ aug_tgt,
    float* __restrict__ ws)
{
    const int bid = blockIdx.x;
    const int t = threadIdx.x;

    if (bid < ALIGN_B0) {
        // ---- MEL: 1280 units/block, 15 float4 loads issued up front ----
        const int base = bid * 1280 + t;             // float4-unit index
        vfloat4 a[5], p[5], tt[5];
#pragma unroll
        for (int k = 0; k < 5; k++) a[k]  = ntload(mel_out  + 4 * (base + 256 * k));
#pragma unroll
        for (int k = 0; k < 5; k++) p[k]  = ntload(mel_post + 4 * (base + 256 * k));
#pragma unroll
        for (int k = 0; k < 5; k++) tt[k] = ntload(mel_tgt  + 4 * (base + 256 * k));
        float s0 = 0.f, s1 = 0.f, d;
#pragma unroll
        for (int k = 0; k < 5; k++) {
            d = a[k][0] - tt[k][0]; s0 = fmaf(d, d, s0);
            d = a[k][1] - tt[k][1]; s1 = fmaf(d, d, s1);
            d = a[k][2] - tt[k][2]; s0 = fmaf(d, d, s0);
            d = a[k][3] - tt[k][3]; s1 = fmaf(d, d, s1);
            d = p[k][0] - tt[k][0]; s0 = fmaf(d, d, s0);
            d = p[k][1] - tt[k][1]; s1 = fmaf(d, d, s1);
            d = p[k][2] - tt[k][2]; s0 = fmaf(d, d, s0);
            d = p[k][3] - tt[k][3]; s1 = fmaf(d, d, s1);
        }
        blockReduceStore(s0 + s1, &ws[P_MEL + bid]);
    } else if (bid < GATE_B0) {
        // ---- ALIGN: 4096 units/block (16 loads), 1024-unit tail block ----
        const int b = bid - ALIGN_B0;
        float s = 0.f;
        if (b < ALIGN_FULL) {
            const int base = b * 4096 + t;
            vfloat4 r[16];
#pragma unroll
            for (int k = 0; k < 16; k++) r[k] = ntload(align + 4 * (base + 256 * k));
#pragma unroll
            for (int k = 0; k < 16; k++) s += alignContrib(base + 256 * k, r[k]);
        } else {
            const int base = ALIGN_FULL * 4096 + t;  // last 1024 units exactly
            vfloat4 r[4];
#pragma unroll
            for (int k = 0; k < 4; k++) r[k] = ntload(align + 4 * (base + 256 * k));
#pragma unroll
            for (int k = 0; k < 4; k++) s += alignContrib(base + 256 * k, r[k]);
        }
        blockReduceStore(s, &ws[P_ALIGN + b]);
    } else if (bid < SPK_B0) {
        // ---- GATE: 4 predicated float4 loads ----
        const int b = bid - GATE_B0;
        const int base = b * 1024 + t;
        float s = 0.f;
#pragma unroll
        for (int k = 0; k < 4; k++) {
            const int u = base + 256 * k;
            if (u < U_GATE) {
                vfloat4 x = ntload(gate_out + 4 * u);
                vfloat4 y = ntload(gate_tgt + 4 * u);
#pragma unroll
                for (int j = 0; j < 4; j++) {
                    float xx = x[j];
                    // softplus(x) = max(x,0) + log1p(exp(-|x|))
                    float sp = fmaxf(xx, 0.f) + log1pf(__expf(-fabsf(xx)));
                    s += sp - xx * y[j];
                }
            }
        }
        blockReduceStore(s, &ws[P_GATE + b]);
    } else if (bid < AUG_B0) {
        // ---- SPEAKER CE: one wave per row, coalesced columns ----
        const int lane = t & 63;
        const int row = (bid - SPK_B0) * 4 + (t >> 6);
        const float* xrow = spk_out + row * NSPK;
        const float* trow = spk_tgt + row * NSPK;
        const int c1 = lane + 64;
        const bool v1 = (c1 < NSPK);
        float x0 = xrow[lane];
        float x1 = v1 ? xrow[c1] : -1e30f;
        float t0 = trow[lane];
        float t1 = v1 ? trow[c1] : -1e30f;

        float mx = waveAllReduceMax(fmaxf(x0, x1));
        float se = waveAllReduceSum(__expf(x0 - mx) + (v1 ? __expf(x1 - mx) : 0.f));
        float bv = (t1 > t0) ? t1 : t0;
        int   bi = (t1 > t0) ? c1 : lane;
        waveAllReduceArgMax(bv, bi);
        float sel = ((lane == bi) ? x0 : 0.f) + ((v1 && c1 == bi) ? x1 : 0.f);
        float xlab = waveAllReduceSum(sel);
        if (lane == 0) {
            ws[P_SPK + row] = -(xlab - mx - __logf(se));   // distinct slot per row
        }
    } else {
        // ---- AUGMENT CE: one wave per row (10 cols in lanes 0..9) ----
        const int lane = t & 63;
        const int row = (bid - AUG_B0) * 4 + (t >> 6);
        const bool v0 = (lane < NAUG);
        const float* xrow = aug_out + row * NAUG;
        const float* trow = aug_tgt + row * NAUG;
        float x0 = v0 ? xrow[lane] : -1e30f;
        float t0 = v0 ? trow[lane] : -1e30f;

        float mx = waveAllReduceMax(x0);
        float se = waveAllReduceSum(v0 ? __expf(x0 - mx) : 0.f);
        float bv = t0; int bi = v0 ? lane : 0x7fffffff;
        waveAllReduceArgMax(bv, bi);
        float xlab = waveAllReduceSum((v0 && lane == bi) ? x0 : 0.f);
        if (lane == 0) {
            ws[P_AUG + row] = -(xlab - mx - __logf(se));   // distinct slot per row
        }
    }
}

// Kernel 2: finalize. One block reduces the ~1.9k partials (8 KB, L2/L3-hot)
// and writes the 5 outputs. Kernel boundary provides visibility of k1 stores.
__global__ __launch_bounds__(BLOCK) void tacotron2_loss_finalize(
    const float* __restrict__ ws, float* __restrict__ out)
{
    const int t = threadIdx.x;
    float s_mel = 0.f, s_align = 0.f, s_gate = 0.f, s_spk = 0.f, s_aug = 0.f;

    for (int i = t; i < MEL_NB; i += BLOCK)   s_mel   += ws[P_MEL + i];
    for (int i = t; i < ALIGN_NB; i += BLOCK) s_align += ws[P_ALIGN + i];
    if (t < GATE_NB) s_gate = ws[P_GATE + t];
    if (t < 64)      s_spk  = ws[P_SPK + t];
    if (t < 64)      s_aug  = ws[P_AUG + t];

    __shared__ float smem[5][4];
    const int lane = t & 63;
    const int wid = t >> 6;
    s_mel   = waveReduceSum(s_mel);
    s_align = waveReduceSum(s_align);
    s_gate  = waveReduceSum(s_gate);
    s_spk   = waveReduceSum(s_spk);
    s_aug   = waveReduceSum(s_aug);
    if (lane == 0) {
        smem[0][wid] = s_mel;
        smem[1][wid] = s_align;
        smem[2][wid] = s_gate;
        smem[3][wid] = s_spk;
        smem[4][wid] = s_aug;
    }
    __syncthreads();

    if (t == 0) {
        float mel_sum   = smem[0][0] + smem[0][1] + smem[0][2] + smem[0][3];
        float align_sum = smem[1][0] + smem[1][1] + smem[1][2] + smem[1][3];
        float gate_sum  = smem[2][0] + smem[2][1] + smem[2][2] + smem[2][3];
        float spk_sum   = smem[3][0] + smem[3][1] + smem[3][2] + smem[3][3];
        float aug_sum   = smem[4][0] + smem[4][1] + smem[4][2] + smem[4][3];

        float mel_loss  = mel_sum  * (1.0f / (float)N_MEL);
        float gate_loss = gate_sum * (1.0f / (float)N_GATE);
        float spk_loss  = spk_sum  * (1.0f / (float)BATCH);
        float aug_loss  = aug_sum  * (1.0f / (float)BATCH);
        float align_loss = fabsf(align_sum) * 0.0005f;
        float tmp = mel_loss + gate_loss;
        float total = 10.0f * tmp + 0.1f * (spk_loss + aug_loss) + align_loss;

        out[0] = total;
        out[1] = tmp;
        out[2] = spk_loss;
        out[3] = aug_loss;
        out[4] = align_loss;
    }
}

extern "C" void kernel_launch(void* const* d_in, const int* in_sizes, int n_in,
                              void* d_out, int out_size, void* d_ws, size_t ws_size,
                              hipStream_t stream) {
    const float* mel_out  = (const float*)d_in[0];
    const float* mel_post = (const float*)d_in[1];
    const float* gate_out = (const float*)d_in[2];
    const float* align    = (const float*)d_in[3];
    const float* spk_out  = (const float*)d_in[4];
    const float* aug_out  = (const float*)d_in[5];
    const float* mel_tgt  = (const float*)d_in[6];
    const float* gate_tgt = (const float*)d_in[7];
    const float* spk_tgt  = (const float*)d_in[8];
    const float* aug_tgt  = (const float*)d_in[9];
    // d_in[10] = step (unused by the loss values)

    float* ws = (float*)d_ws;
    float* out = (float*)d_out;

    tacotron2_loss_reduce<<<dim3(GRID), dim3(BLOCK), 0, stream>>>(
        mel_out, mel_post, gate_out, align, spk_out, aug_out,
        mel_tgt, gate_tgt, spk_tgt, aug_tgt, ws);

    tacotron2_loss_finalize<<<dim3(1), dim3(BLOCK), 0, stream>>>(ws, out);
}